// Round 5
// baseline (66037.115 us; speedup 1.0000x reference)
//
#include <hip/hip_runtime.h>
#include <hip/hip_cooperative_groups.h>
#include <stdint.h>

namespace cg = cooperative_groups;

#define HD   1024
#define FH   4096
#define TT   256
#define BAT  1024
#define BM   128
#define BN   128
#define BK   64

typedef __bf16 bf16_t;
typedef __bf16 bf16x8 __attribute__((ext_vector_type(8)));
typedef float  f32x4  __attribute__((ext_vector_type(4)));

__device__ __forceinline__ float sigm(float x)     { return 1.0f/(1.0f + __expf(-x)); }
__device__ __forceinline__ float tanhfast(float x) { return 1.0f - 2.0f/(__expf(2.0f*x) + 1.0f); }

__device__ __forceinline__ void gload_lds16(const void* g, void* l) {
    __builtin_amdgcn_global_load_lds((const __attribute__((address_space(1))) void*)g,
                                     (__attribute__((address_space(3))) void*)l, 16, 0, 0);
}

// Permutation: p = nt*128 + cb*64 + g*16 + low  (nt<32, cb<2, g<4, low<16)
//   unit = nt*32 + cb*16 + low ; orig W row = g*1024 + unit
// Storage swizzle (T2, rule #21): element u of row r stored at u ^ ((r&7)<<3).
__global__ void prep_weights(const float* __restrict__ Whh0, const float* __restrict__ Wih1,
                             const float* __restrict__ Whh1, const float* __restrict__ bih0,
                             const float* __restrict__ bhh0, const float* __restrict__ bih1,
                             const float* __restrict__ bhh1, const float* __restrict__ Wih0,
                             bf16_t* __restrict__ W0p, bf16_t* __restrict__ W1cat,
                             float* __restrict__ bias0p, float* __restrict__ bias1p,
                             float* __restrict__ wih0p)
{
    int p   = blockIdx.x;            // 0..4095
    int nt  = p >> 7;
    int c   = p & 127;
    int cb  = c >> 6;
    int g   = (c >> 4) & 3;
    int low = c & 15;
    int unit = nt*32 + cb*16 + low;
    int orig = g*HD + unit;
    int swz  = (p & 7) << 3;

    const float* s0 = Whh0 + (size_t)orig*HD;
    const float* s1 = Wih1 + (size_t)orig*HD;
    const float* s2 = Whh1 + (size_t)orig*HD;
    bf16_t* d0 = W0p   + (size_t)p*HD;
    bf16_t* d1 = W1cat + (size_t)p*2048;
    for (int k = threadIdx.x; k < HD; k += blockDim.x) {
        int ks = k ^ swz;
        d0[ks]        = (bf16_t)s0[k];
        d1[ks]        = (bf16_t)s1[k];
        d1[1024 + ks] = (bf16_t)s2[k];
    }
    if (threadIdx.x == 0) {
        bias0p[p] = bih0[orig] + bhh0[orig];
        bias1p[p] = bih1[orig] + bhh1[orig];
        wih0p[p]  = Wih0[orig];
    }
}

__global__ void init_states(const float* __restrict__ h0,
                            bf16_t* __restrict__ C0, bf16_t* __restrict__ C1)
{
    int i = blockIdx.x * blockDim.x + threadIdx.x;   // 0 .. 1048575
    int row = i >> 10, u = i & 1023;
    int us = u ^ ((row & 7) << 3);
    C1[(size_t)row*2048 + us]        = (bf16_t)h0[i];            // ha_{-1}
    C0[(size_t)row*2048 + 1024 + us] = (bf16_t)h0[1048576 + i];  // hb_{-1}
}

// 128x128 tile GEMM accumulate: acc += A(rows mt*128.., swizzled, stride 2048)
//                                     @ B^T(rows nt*128.., swizzled, stride Bstr)
template<int NSTEP>
__device__ __forceinline__ void gemm_tile(
    const bf16_t* __restrict__ A, const bf16_t* __restrict__ B, int Bstr,
    char* ldsc, int mt, int nt, int w, int lane, int rb, int cb,
    f32x4 acc[2][4])
{
    int srow = lane >> 3;
    int skb  = (lane & 7) * 16;
    int l15  = lane & 15, lg = lane >> 4;

    auto stage = [&](int buf, int k0) {
        char* base = ldsc + buf*32768;
        #pragma unroll
        for (int q = 0; q < 4; ++q) {
            int c = w*4 + q;                    // 0..31, wave-uniform
            int rl = (c & 15)*8 + srow;
            const char* src;
            if (c < 16) src = (const char*)(A + (size_t)(mt*BM + rl)*2048 + k0) + skb;
            else        src = (const char*)(B + (size_t)(nt*BN + rl)*(size_t)Bstr + k0) + skb;
            gload_lds16(src, base + c*1024);    // HW scatters lane*16
        }
    };

    stage(0, 0);
    #pragma unroll 1
    for (int s = 0; s < NSTEP; ++s) {
        __syncthreads();                        // drains vmcnt+lgkmcnt
        if (s + 1 < NSTEP) stage((s + 1) & 1, (s + 1)*BK);
        const char* lb = ldsc + (s & 1)*32768;
        #pragma unroll
        for (int ks = 0; ks < 2; ++ks) {
            bf16x8 af[2], bfr[4];
            #pragma unroll
            for (int mi = 0; mi < 2; ++mi) {
                int ar = rb*32 + mi*16 + l15;
                af[mi] = *(const bf16x8*)(lb + ar*128 + ((ks*64 + lg*16) ^ ((ar & 7) << 4)));
            }
            #pragma unroll
            for (int nj = 0; nj < 4; ++nj) {
                int br = cb*64 + nj*16 + l15;
                bfr[nj] = *(const bf16x8*)(lb + 16384 + br*128 + ((ks*64 + lg*16) ^ ((br & 7) << 4)));
            }
            #pragma unroll
            for (int mi = 0; mi < 2; ++mi)
                #pragma unroll
                for (int nj = 0; nj < 4; ++nj)
                    acc[mi][nj] = __builtin_amdgcn_mfma_f32_16x16x32_bf16(af[mi], bfr[nj], acc[mi][nj], 0,0,0);
        }
    }
}

// Persistent 2-layer LSTM loop: 256 blocks (1/CU), grid barrier between phases.
__global__ __launch_bounds__(512, 2) void lstm_persist(
    const bf16_t* __restrict__ W0p, const bf16_t* __restrict__ W1cat,
    const float* __restrict__ bias0p, const float* __restrict__ bias1p,
    const float* __restrict__ wih0p, const float* __restrict__ c0in,
    bf16_t* __restrict__ Cbuf0, bf16_t* __restrict__ Cbuf1,
    const float* __restrict__ Wout, const float* __restrict__ bout,
    float* __restrict__ preds)
{
    __shared__ bf16_t lds[2*16384];             // 64 KiB
    cg::grid_group grid = cg::this_grid();

    int xcd = blockIdx.x & 7;
    int bi  = blockIdx.x >> 3;
    int nt  = xcd*4 + (bi & 3);                 // B-tiles XCD-exclusive (fixed residency)
    int mt  = bi >> 2;
    int tid = threadIdx.x;
    int lane = tid & 63, w = tid >> 6;
    int rb = w >> 1, cb = w & 1;
    int l15 = lane & 15, lg = lane >> 4;
    char* ldsc = (char*)lds;

    int pbase = nt*128 + cb*64 + l15;
    int j = nt*32 + cb*16 + l15;                // hidden unit owned by this lane
    float bi0[4], wv0[4], bi1[4];
    #pragma unroll
    for (int g = 0; g < 4; ++g) {
        bi0[g] = bias0p[pbase + g*16];
        wv0[g] = wih0p[pbase + g*16];
        bi1[g] = bias1p[pbase + g*16];
    }
    float wout = Wout[j];
    float bo   = bout[0];

    // c-state resident in registers for the whole sequence
    float c0s[2][4], c1s[2][4];
    #pragma unroll
    for (int mi = 0; mi < 2; ++mi)
        #pragma unroll
        for (int r = 0; r < 4; ++r) {
            int row = mt*BM + rb*32 + mi*16 + lg*4 + r;
            c0s[mi][r] = c0in[(size_t)row*HD + j];
            c1s[mi][r] = c0in[1048576 + (size_t)row*HD + j];
        }

    bf16_t* Cb[2] = { Cbuf0, Cbuf1 };

    #pragma unroll 1
    for (int t = 0; t < TT; ++t) {
        bf16_t* Cprev = Cb[(t + 1) & 1];        // ha_{t-1} in cols 0:1024
        bf16_t* Ccur  = Cb[t & 1];              // gets ha_t; holds hb_{t-1} in cols 1024:2048

        // ---------------- phase 0: layer-0 GEMM + cell ----------------
        f32x4 acc[2][4];
        #pragma unroll
        for (int a_ = 0; a_ < 2; ++a_)
            #pragma unroll
            for (int b_ = 0; b_ < 4; ++b_) acc[a_][b_] = f32x4{0.f,0.f,0.f,0.f};
        gemm_tile<16>(Cprev, W0p, 1024, ldsc, mt, nt, w, lane, rb, cb, acc);

        #pragma unroll
        for (int mi = 0; mi < 2; ++mi) {
            #pragma unroll
            for (int r = 0; r < 4; ++r) {
                int row = mt*BM + rb*32 + mi*16 + lg*4 + r;
                float x = (t > 0) ? preds[(size_t)row*TT + (t-1)] : 0.f;
                float gi = acc[mi][0][r] + bi0[0] + x*wv0[0];
                float gf = acc[mi][1][r] + bi0[1] + x*wv0[1];
                float gg = acc[mi][2][r] + bi0[2] + x*wv0[2];
                float go = acc[mi][3][r] + bi0[3] + x*wv0[3];
                float cn = sigm(gf)*c0s[mi][r] + sigm(gi)*tanhfast(gg);
                c0s[mi][r] = cn;
                Ccur[(size_t)row*2048 + (j ^ ((row & 7) << 3))] = (bf16_t)(sigm(go)*tanhfast(cn));
            }
        }
        __threadfence();
        grid.sync();
        __threadfence();

        // ---------------- phase 1: layer-1 merged GEMM (K=2048) + cell + pred ----------------
        #pragma unroll
        for (int a_ = 0; a_ < 2; ++a_)
            #pragma unroll
            for (int b_ = 0; b_ < 4; ++b_) acc[a_][b_] = f32x4{0.f,0.f,0.f,0.f};
        gemm_tile<32>(Ccur, W1cat, 2048, ldsc, mt, nt, w, lane, rb, cb, acc);

        #pragma unroll
        for (int mi = 0; mi < 2; ++mi) {
            #pragma unroll
            for (int r = 0; r < 4; ++r) {
                int row = mt*BM + rb*32 + mi*16 + lg*4 + r;
                float gi = acc[mi][0][r] + bi1[0];
                float gf = acc[mi][1][r] + bi1[1];
                float gg = acc[mi][2][r] + bi1[2];
                float go = acc[mi][3][r] + bi1[3];
                float cn = sigm(gf)*c1s[mi][r] + sigm(gi)*tanhfast(gg);
                c1s[mi][r] = cn;
                float h = sigm(go)*tanhfast(cn);
                Cprev[(size_t)row*2048 + 1024 + (j ^ ((row & 7) << 3))] = (bf16_t)h;
                float v = h * wout;
                v += __shfl_xor(v, 1, 64);
                v += __shfl_xor(v, 2, 64);
                v += __shfl_xor(v, 4, 64);
                v += __shfl_xor(v, 8, 64);
                if (l15 == 0) {
                    if (nt == 0 && cb == 0) v += bo;
                    atomicAdd(&preds[(size_t)row*TT + t], v);
                }
            }
        }
        __threadfence();
        grid.sync();
        __threadfence();
    }
}

__global__ void loss_kernel(const float* __restrict__ preds, const float* __restrict__ targets,
                            float* __restrict__ lossp)
{
    int i = blockIdx.x * blockDim.x + threadIdx.x;   // 0 .. 262143
    float d = preds[i] - targets[i];
    float v = d*d;
    v += __shfl_xor(v, 1, 64);
    v += __shfl_xor(v, 2, 64);
    v += __shfl_xor(v, 4, 64);
    v += __shfl_xor(v, 8, 64);
    v += __shfl_xor(v, 16, 64);
    v += __shfl_xor(v, 32, 64);
    if ((threadIdx.x & 63) == 0) atomicAdd(lossp, v * (1.0f/1024.0f));
}

extern "C" void kernel_launch(void* const* d_in, const int* in_sizes, int n_in,
                              void* d_out, int out_size, void* d_ws, size_t ws_size,
                              hipStream_t stream)
{
    const float* outputs = (const float*)d_in[0];
    const float* h0      = (const float*)d_in[1];
    const float* c0      = (const float*)d_in[2];
    const float* Wih0    = (const float*)d_in[3];
    const float* Whh0    = (const float*)d_in[4];
    const float* bih0    = (const float*)d_in[5];
    const float* bhh0    = (const float*)d_in[6];
    const float* Wih1    = (const float*)d_in[7];
    const float* Whh1    = (const float*)d_in[8];
    const float* bih1    = (const float*)d_in[9];
    const float* bhh1    = (const float*)d_in[10];
    const float* Wout    = (const float*)d_in[11];
    const float* bout    = (const float*)d_in[12];

    uint8_t* ws = (uint8_t*)d_ws;
    size_t o = 0;
    auto alloc = [&](size_t bytes) { void* p = ws + o; o += (bytes + 255) & ~(size_t)255; return p; };
    bf16_t* W0p    = (bf16_t*)alloc((size_t)FH*HD*2);        // 8 MB, permuted+swizzled
    bf16_t* W1cat  = (bf16_t*)alloc((size_t)FH*2048*2);      // 16 MB, [Wih1|Whh1] permuted+swizzled
    bf16_t* Cbuf0  = (bf16_t*)alloc((size_t)BAT*2048*2);     // 4 MB, [ha|hb] swizzled
    bf16_t* Cbuf1  = (bf16_t*)alloc((size_t)BAT*2048*2);
    float*  bias0p = (float*)alloc(FH*4);
    float*  bias1p = (float*)alloc(FH*4);
    float*  wih0p  = (float*)alloc(FH*4);

    float* preds = (float*)d_out;                            // [BAT][TT] then loss scalar
    hipMemsetAsync(d_out, 0, (size_t)out_size*4, stream);

    prep_weights<<<FH, 256, 0, stream>>>(Whh0, Wih1, Whh1, bih0, bhh0, bih1, bhh1, Wih0,
                                         W0p, W1cat, bias0p, bias1p, wih0p);
    init_states<<<4096, 256, 0, stream>>>(h0, Cbuf0, Cbuf1);

    void* args[] = { (void*)&W0p, (void*)&W1cat, (void*)&bias0p, (void*)&bias1p,
                     (void*)&wih0p, (void*)&c0, (void*)&Cbuf0, (void*)&Cbuf1,
                     (void*)&Wout, (void*)&bout, (void*)&preds };
    hipLaunchCooperativeKernel((const void*)lstm_persist, dim3(256), dim3(512),
                               args, 0, stream);

    loss_kernel<<<1024, 256, 0, stream>>>(preds, outputs, preds + (size_t)BAT*TT);
}

// Round 6
// 10803.069 us; speedup vs baseline: 6.1128x; 6.1128x over previous
//
#include <hip/hip_runtime.h>
#include <stdint.h>

#define HD   1024
#define FH   4096
#define TT   256
#define BAT  1024
#define BM   64
#define BN   128   // gate-cols per block
#define BK   64

typedef __bf16 bf16_t;
typedef __bf16 bf16x8 __attribute__((ext_vector_type(8)));
typedef float  f32x4  __attribute__((ext_vector_type(4)));

__device__ __forceinline__ float sigm(float x)     { return 1.0f/(1.0f + __expf(-x)); }
__device__ __forceinline__ float tanhfast(float x) { return 1.0f - 2.0f/(__expf(2.0f*x) + 1.0f); }

__device__ __forceinline__ void gload_lds16(const void* g, void* l) {
    __builtin_amdgcn_global_load_lds((const __attribute__((address_space(1))) void*)g,
                                     (__attribute__((address_space(3))) void*)l, 16, 0, 0);
}

// Permutation: p = nt*128 + cb*64 + g*16 + low  (nt<32, cb<2, g<4, low<16)
//   unit = nt*32 + cb*16 + low ; orig W row = g*1024 + unit
// Storage swizzle (T2, rule #21): element u of row r stored at u ^ ((r&7)<<3).
__global__ void prep_weights(const float* __restrict__ Whh0, const float* __restrict__ Wih1,
                             const float* __restrict__ Whh1, const float* __restrict__ bih0,
                             const float* __restrict__ bhh0, const float* __restrict__ bih1,
                             const float* __restrict__ bhh1, const float* __restrict__ Wih0,
                             bf16_t* __restrict__ W0p, bf16_t* __restrict__ W1cat,
                             float* __restrict__ bias0p, float* __restrict__ bias1p,
                             float* __restrict__ wih0p)
{
    int p   = blockIdx.x;            // 0..4095
    int nt  = p >> 7;
    int c   = p & 127;
    int cb  = c >> 6;
    int g   = (c >> 4) & 3;
    int low = c & 15;
    int unit = nt*32 + cb*16 + low;
    int orig = g*HD + unit;
    int swz  = (p & 7) << 3;

    const float* s0 = Whh0 + (size_t)orig*HD;
    const float* s1 = Wih1 + (size_t)orig*HD;
    const float* s2 = Whh1 + (size_t)orig*HD;
    bf16_t* d0 = W0p   + (size_t)p*HD;
    bf16_t* d1 = W1cat + (size_t)p*2048;
    for (int k = threadIdx.x; k < HD; k += blockDim.x) {
        int ks = k ^ swz;
        d0[ks]        = (bf16_t)s0[k];
        d1[ks]        = (bf16_t)s1[k];
        d1[1024 + ks] = (bf16_t)s2[k];
    }
    if (threadIdx.x == 0) {
        bias0p[p] = bih0[orig] + bhh0[orig];
        bias1p[p] = bih1[orig] + bhh1[orig];
        wih0p[p]  = Wih0[orig];
    }
}

__global__ void init_states(const float* __restrict__ h0, const float* __restrict__ c0in,
                            bf16_t* __restrict__ C0, bf16_t* __restrict__ C1,
                            float* __restrict__ cl0, float* __restrict__ cl1)
{
    int i = blockIdx.x * blockDim.x + threadIdx.x;   // 0 .. 1048575
    int row = i >> 10, u = i & 1023;
    int us = u ^ ((row & 7) << 3);
    C1[(size_t)row*2048 + us]        = (bf16_t)h0[i];            // ha_{-1}
    C0[(size_t)row*2048 + 1024 + us] = (bf16_t)h0[1048576 + i];  // hb_{-1}
    cl0[i] = c0in[i];
    cl1[i] = c0in[1048576 + i];
}

// One step-GEMM: gates[BAT][4096] = A(BAT x KTOT, swizzled, stride 2048) @ B^T (4096 x KTOT, swizzled)
// Grid 512 = 16 mt x 32 nt (XCD-exclusive nt), 256 threads (4 waves) -> 2 blocks/CU.
// LAYER 0: KTOT=1024, + x*wih0 rank-1 term, cell -> ha into Hout (swizzled), c in cst.
// LAYER 1: KTOT=2048 (A = [ha|hb]),          cell -> hb into Hout (swizzled), + pred atomicAdd.
template<int LAYER>
__global__ __launch_bounds__(256, 4) void step_kernel(
    const bf16_t* __restrict__ A, const bf16_t* __restrict__ B, int Bstride,
    const float* __restrict__ biasp, const float* __restrict__ wih0p,
    bf16_t* __restrict__ Hout, float* __restrict__ cst,
    const float* __restrict__ Wout, const float* __restrict__ bout,
    float* __restrict__ preds, int t)
{
    constexpr int KTOT  = (LAYER == 0) ? 1024 : 2048;
    constexpr int NSTEP = KTOT / BK;

    __shared__ bf16_t lds[2*12288];             // 2 bufs x (A 64x64 + B 128x64 elems) = 48 KiB

    int xcd = blockIdx.x & 7;
    int bi  = blockIdx.x >> 3;                  // 0..63
    int nt  = xcd*4 + (bi & 3);                 // 0..31  (B-tiles XCD-exclusive)
    int mt  = bi >> 2;                          // 0..15
    int tid = threadIdx.x;
    int lane = tid & 63, w = tid >> 6;          // 4 waves
    int rb = w >> 1, cb = w & 1;
    int l15 = lane & 15, lg = lane >> 4;

    int srow = lane >> 3;                       // staging: row within 8-row chunk
    int skb  = (lane & 7) * 16;                 // staging: byte within 128B row
    char* ldsc = (char*)lds;

    f32x4 acc[2][4];
    #pragma unroll
    for (int a_ = 0; a_ < 2; ++a_)
        #pragma unroll
        for (int b_ = 0; b_ < 4; ++b_) acc[a_][b_] = f32x4{0.f,0.f,0.f,0.f};

    auto stage = [&](int buf, int k0) {
        char* base = ldsc + buf*24576;
        #pragma unroll
        for (int q = 0; q < 6; ++q) {
            int c = w*6 + q;                    // 0..23, wave-uniform
            const char* src;
            if (c < 8) {                        // A: 64 rows
                int rl = c*8 + srow;
                src = (const char*)(A + (size_t)(mt*BM + rl)*2048 + k0) + skb;
            } else {                            // B: 128 rows
                int rl = (c - 8)*8 + srow;
                src = (const char*)(B + (size_t)(nt*BN + rl)*(size_t)Bstride + k0) + skb;
            }
            gload_lds16(src, base + c*1024);    // HW scatters lane*16
        }
    };

    stage(0, 0);
    #pragma unroll 1
    for (int s = 0; s < NSTEP; ++s) {
        __syncthreads();                        // drains vmcnt+lgkmcnt
        if (s + 1 < NSTEP) stage((s + 1) & 1, (s + 1)*BK);
        const char* lb = ldsc + (s & 1)*24576;
        #pragma unroll
        for (int ks = 0; ks < 2; ++ks) {
            bf16x8 af[2], bfr[4];
            #pragma unroll
            for (int mi = 0; mi < 2; ++mi) {
                int ar = rb*32 + mi*16 + l15;   // 0..63
                af[mi] = *(const bf16x8*)(lb + ar*128 + ((ks*64 + lg*16) ^ ((ar & 7) << 4)));
            }
            #pragma unroll
            for (int nj = 0; nj < 4; ++nj) {
                int br = cb*64 + nj*16 + l15;   // 0..127
                bfr[nj] = *(const bf16x8*)(lb + 8192 + br*128 + ((ks*64 + lg*16) ^ ((br & 7) << 4)));
            }
            #pragma unroll
            for (int mi = 0; mi < 2; ++mi)
                #pragma unroll
                for (int nj = 0; nj < 4; ++nj)
                    acc[mi][nj] = __builtin_amdgcn_mfma_f32_16x16x32_bf16(af[mi], bfr[nj], acc[mi][nj], 0,0,0);
        }
    }

    // ---------------- epilogue ----------------
    int pbase = nt*128 + cb*64 + l15;
    float bi4[4];
    #pragma unroll
    for (int g = 0; g < 4; ++g) bi4[g] = biasp[pbase + g*16];
    int j = nt*32 + cb*16 + l15;                // hidden unit owned by this lane

    if (LAYER == 0) {
        float wv[4];
        #pragma unroll
        for (int g = 0; g < 4; ++g) wv[g] = wih0p[pbase + g*16];
        #pragma unroll
        for (int mi = 0; mi < 2; ++mi) {
            #pragma unroll
            for (int r = 0; r < 4; ++r) {
                int row = mt*BM + rb*32 + mi*16 + lg*4 + r;
                float x = (t > 0) ? preds[(size_t)row*TT + (t-1)] : 0.f;
                float gi = acc[mi][0][r] + bi4[0] + x*wv[0];
                float gf = acc[mi][1][r] + bi4[1] + x*wv[1];
                float gg = acc[mi][2][r] + bi4[2] + x*wv[2];
                float go = acc[mi][3][r] + bi4[3] + x*wv[3];
                size_t coff = (size_t)row*HD + j;
                float cn = sigm(gf)*cst[coff] + sigm(gi)*tanhfast(gg);
                cst[coff] = cn;
                Hout[(size_t)row*2048 + (j ^ ((row & 7) << 3))] = (bf16_t)(sigm(go)*tanhfast(cn));
            }
        }
    } else {
        float wout = Wout[j];
        #pragma unroll
        for (int mi = 0; mi < 2; ++mi) {
            #pragma unroll
            for (int r = 0; r < 4; ++r) {
                int row = mt*BM + rb*32 + mi*16 + lg*4 + r;
                float gi = acc[mi][0][r] + bi4[0];
                float gf = acc[mi][1][r] + bi4[1];
                float gg = acc[mi][2][r] + bi4[2];
                float go = acc[mi][3][r] + bi4[3];
                size_t coff = (size_t)row*HD + j;
                float cn = sigm(gf)*cst[coff] + sigm(gi)*tanhfast(gg);
                cst[coff] = cn;
                float h = sigm(go)*tanhfast(cn);
                Hout[(size_t)row*2048 + (j ^ ((row & 7) << 3))] = (bf16_t)h;
                float v = h * wout;
                v += __shfl_xor(v, 1, 64);
                v += __shfl_xor(v, 2, 64);
                v += __shfl_xor(v, 4, 64);
                v += __shfl_xor(v, 8, 64);
                if (l15 == 0) {
                    if (nt == 0 && cb == 0) v += bout[0];
                    atomicAdd(&preds[(size_t)row*TT + t], v);
                }
            }
        }
    }
}

__global__ void loss_kernel(const float* __restrict__ preds, const float* __restrict__ targets,
                            float* __restrict__ lossp)
{
    int i = blockIdx.x * blockDim.x + threadIdx.x;   // 0 .. 262143
    float d = preds[i] - targets[i];
    float v = d*d;
    v += __shfl_xor(v, 1, 64);
    v += __shfl_xor(v, 2, 64);
    v += __shfl_xor(v, 4, 64);
    v += __shfl_xor(v, 8, 64);
    v += __shfl_xor(v, 16, 64);
    v += __shfl_xor(v, 32, 64);
    if ((threadIdx.x & 63) == 0) atomicAdd(lossp, v * (1.0f/1024.0f));
}

extern "C" void kernel_launch(void* const* d_in, const int* in_sizes, int n_in,
                              void* d_out, int out_size, void* d_ws, size_t ws_size,
                              hipStream_t stream)
{
    const float* outputs = (const float*)d_in[0];
    const float* h0      = (const float*)d_in[1];
    const float* c0      = (const float*)d_in[2];
    const float* Wih0    = (const float*)d_in[3];
    const float* Whh0    = (const float*)d_in[4];
    const float* bih0    = (const float*)d_in[5];
    const float* bhh0    = (const float*)d_in[6];
    const float* Wih1    = (const float*)d_in[7];
    const float* Whh1    = (const float*)d_in[8];
    const float* bih1    = (const float*)d_in[9];
    const float* bhh1    = (const float*)d_in[10];
    const float* Wout    = (const float*)d_in[11];
    const float* bout    = (const float*)d_in[12];

    uint8_t* ws = (uint8_t*)d_ws;
    size_t o = 0;
    auto alloc = [&](size_t bytes) { void* p = ws + o; o += (bytes + 255) & ~(size_t)255; return p; };
    bf16_t* W0p    = (bf16_t*)alloc((size_t)FH*HD*2);        // 8 MB, permuted+swizzled
    bf16_t* W1cat  = (bf16_t*)alloc((size_t)FH*2048*2);      // 16 MB, [Wih1|Whh1] permuted+swizzled
    bf16_t* Cbuf0  = (bf16_t*)alloc((size_t)BAT*2048*2);     // 4 MB, [ha|hb] swizzled
    bf16_t* Cbuf1  = (bf16_t*)alloc((size_t)BAT*2048*2);
    float*  cl0    = (float*)alloc((size_t)BAT*HD*4);
    float*  cl1    = (float*)alloc((size_t)BAT*HD*4);
    float*  bias0p = (float*)alloc(FH*4);
    float*  bias1p = (float*)alloc(FH*4);
    float*  wih0p  = (float*)alloc(FH*4);
    bf16_t* Cb[2]  = { Cbuf0, Cbuf1 };

    float* preds = (float*)d_out;                            // [BAT][TT] then loss scalar
    hipMemsetAsync(d_out, 0, (size_t)out_size*4, stream);

    prep_weights<<<FH, 256, 0, stream>>>(Whh0, Wih1, Whh1, bih0, bhh0, bih1, bhh1, Wih0,
                                         W0p, W1cat, bias0p, bias1p, wih0p);
    init_states<<<4096, 256, 0, stream>>>(h0, c0, Cbuf0, Cbuf1, cl0, cl1);

    for (int t = 0; t < TT; ++t) {
        bf16_t* Cprev = Cb[(t + 1) & 1];   // holds ha_{t-1} in cols 0:1024
        bf16_t* Ccur  = Cb[t & 1];         // gets ha_t; holds hb_{t-1} in cols 1024:2048
        step_kernel<0><<<512, 256, 0, stream>>>(Cprev, W0p, 1024, bias0p, wih0p,
                                                Ccur, cl0, nullptr, nullptr, preds, t);
        step_kernel<1><<<512, 256, 0, stream>>>(Ccur, W1cat, 2048, bias1p, nullptr,
                                                Cprev + 1024, cl1, Wout, bout, preds, t);
    }
    loss_kernel<<<1024, 256, 0, stream>>>(preds, outputs, preds + (size_t)BAT*TT);
}